// Round 5
// baseline (435.420 us; speedup 1.0000x reference)
//
#include <hip/hip_runtime.h>
#include <hip/hip_bf16.h>

// Problem constants (fixed by setup_inputs)
#define E_    8
#define DIN   2048
#define DOUT  2048
#define N_TOK 4096
#define NK    8192
#define R_    16
#define KEXT  2112            // 2048 + 16 (LoRA rank tail) + 48 zero pad, %64==0
#define KT_N  (KEXT / 64)     // 33 K-tiles

#define XA_B     519          // sum ceil(Me/16) <= 519 (xa blocks first: longest)
#define WCONV_B  4096
#define GATHER_B 8192

typedef __bf16 bf16x8 __attribute__((ext_vector_type(8)));
typedef float  f32x4  __attribute__((ext_vector_type(4)));
typedef unsigned short u16x8 __attribute__((ext_vector_type(8)));

static __device__ __forceinline__ void gld16(const void* g, void* l) {
  __builtin_amdgcn_global_load_lds(
      (const __attribute__((address_space(1))) unsigned int*)g,
      (__attribute__((address_space(3))) unsigned int*)l, 16, 0, 0);
}

static __device__ __forceinline__ unsigned short f2bfu(float f) {
  union { float f; unsigned int u; } v; v.f = f;
  unsigned int r = v.u + 0x7fffu + ((v.u >> 16) & 1u);  // round-to-nearest-even
  return (unsigned short)(r >> 16);
}

static __device__ __forceinline__ bf16x8 cvt8(float4 a, float4 b) {
  u16x8 u;
  u[0] = f2bfu(a.x); u[1] = f2bfu(a.y); u[2] = f2bfu(a.z); u[3] = f2bfu(a.w);
  u[4] = f2bfu(b.x); u[5] = f2bfu(b.y); u[6] = f2bfu(b.z); u[7] = f2bfu(b.w);
  return __builtin_bit_cast(bf16x8, u);
}

// ---- fully-parallel prep: xa | wconv | gather in ONE launch (FROZEN since r4:
// non-gemm time is invariant at ~258us across 4 structurally different preps ->
// harness reset/restore dominated, not prep code) ----
__global__ void __launch_bounds__(256)
k_prep(const float* __restrict__ w, const float* __restrict__ lb,
       unsigned short* __restrict__ wbe,
       const float* __restrict__ la,
       const float* __restrict__ x, const int* __restrict__ ssi,
       const float* __restrict__ gates, const int* __restrict__ kptr,
       unsigned short* __restrict__ Xe, float* __restrict__ gate,
       int* __restrict__ tok, const int* __restrict__ eoff) {
  const int b = blockIdx.x, tid = threadIdx.x;
  if (b < XA_B) {                                   // ---- XA tail ----
    __shared__ f32x4 red[4][64];
    int off_prev = 0, e = -1, m_start = 0, m_end = 0, acc_t = 0;
#pragma unroll
    for (int i = 0; i < E_; i++) {
      int oe = eoff[i];
      int te = (oe - off_prev + 15) >> 4;
      if (e < 0 && b < acc_t + te) {
        e = i; m_start = off_prev + (b - acc_t) * 16; m_end = oe;
      }
      acc_t += te; off_prev = oe;
    }
    if (e < 0) return;
    const int wv = tid >> 6, lane = tid & 63;
    const int l15 = lane & 15, quad = lane >> 4;
    int arow = m_start + l15; if (arow >= m_end) arow = m_end - 1;  // clamp
    const int kk = kptr[0];
    const int trow = ssi[arow] / kk;                // token row for this slot
    const float* xp = x  + (long long)trow * DIN + wv * 512 + quad * 8;
    const float* ap = la + ((long long)e * R_ + l15) * DIN + wv * 512 + quad * 8;
    f32x4 acc = (f32x4){0.f, 0.f, 0.f, 0.f};
#pragma unroll 4
    for (int k0 = 0; k0 < 512; k0 += 32) {
      float4 x0 = *(const float4*)(xp + k0);
      float4 x1 = *(const float4*)(xp + k0 + 4);
      float4 a0 = *(const float4*)(ap + k0);
      float4 a1 = *(const float4*)(ap + k0 + 4);
      acc = __builtin_amdgcn_mfma_f32_16x16x32_bf16(cvt8(x0, x1), cvt8(a0, a1),
                                                    acc, 0, 0, 0);
    }
    red[wv][lane] = acc;
    __syncthreads();
    if (wv == 0) {
      f32x4 s = red[0][lane] + red[1][lane] + red[2][lane] + red[3][lane];
#pragma unroll
      for (int t = 0; t < 4; t++) {
        int slot = m_start + quad * 4 + t;
        if (slot < m_end)
          Xe[(long long)slot * KEXT + 2048 + l15] = f2bfu(2.0f * s[t]);
      }
    }
  } else if (b < XA_B + WCONV_B) {                  // ---- wconv ----
    const int wv = tid >> 6, ln = tid & 63;
    const long long row = (((long long)(b - XA_B)) << 2) | wv;   // e*DOUT + n
    const float4* src  = (const float4*)(w + row * DIN);
    const float4* lsrc = (const float4*)(lb + row * R_);
    ushort4* dst = (ushort4*)(wbe + row * KEXT);
    for (int u = ln; u < KEXT / 4; u += 64) {
      float4 v;
      if (u < 512)       v = src[u];
      else if (u < 516)  v = lsrc[u - 512];
      else               v = make_float4(0.f, 0.f, 0.f, 0.f);
      ushort4 o;
      o.x = f2bfu(v.x); o.y = f2bfu(v.y); o.z = f2bfu(v.z); o.w = f2bfu(v.w);
      dst[u] = o;
    }
  } else {                                          // ---- gather ----
    const int s = b - XA_B - WCONV_B;
    int ssv = ssi[s];
    int kk = kptr[0];
    int t = ssv / kk, sl = ssv - t * kk;
    if (tid == 0) { gate[s] = gates[t * kk + sl]; tok[s] = t; }
    const float4* src = (const float4*)(x + (long long)t * DIN);
    ushort4* dst = (ushort4*)(Xe + (long long)s * KEXT);
    for (int i = tid; i < 512; i += 256) {
      float4 v = src[i];
      ushort4 o;
      o.x = f2bfu(v.x); o.y = f2bfu(v.y); o.z = f2bfu(v.z); o.w = f2bfu(v.w);
      dst[i] = o;
    }
    if (tid < 12) {   // zero cols 2064..2111 (cols 2048..2063 written by xa blocks)
      ushort4 z; z.x = z.y = z.z = z.w = 0;
      dst[516 + tid] = z;
    }
  }
}

// ---- grouped GEMM, ASYMMETRIC 128x256 tile, 16 waves, XCD-locked n-tile ----
// r4 confirmed: staging-rate scales with resident waves (concurrency x L3-latency
// bound). This round keeps the 32-waves/CU ceiling (small acc => VGPR ~40-50 =>
// wave-capped 2 blocks/CU of 16 waves) while cutting staged bytes 25%:
//   staged = 576 x (128+256) x 64 x 2B x 33  = 934 MB   (r4: 1.24 GB)
// and locking BN=256 => exactly 8 n-tiles = 8 XCDs (nt = id&7 matches dispatch
// round-robin). All mt for one nt run on one XCD: the active expert's W slab
// (256 x KEXT x 2B = 1.08 MB) stays in that XCD's 4MB L2, so the 608 MB of
// B-staging becomes mostly L2 hits; Xe (34.6 MB) is L3-resident, read 1x/XCD.
// Same proven XOR swizzle + 2-barrier drain loop (schedule shown neutral r1-r3).
__global__ void __launch_bounds__(1024)
k_gemm(const unsigned short* __restrict__ Xe, const unsigned short* __restrict__ Wbe,
       const float* __restrict__ gate, const int* __restrict__ tok,
       const int* __restrict__ eoff, float* __restrict__ out) {
  __shared__ alignas(16) unsigned short sAB[128 * 64 + 256 * 64];  // A | B, 48 KB

  const int id = blockIdx.x;                 // 576 blocks
  const int nt = id & 7;                     // n-tile == XCD slot
  const int mt = id >> 3;                    // 0..71
  const int n_start = nt << 8;

  // m-tile scan: mt covers sum(ceil(Me/128)) <= 71
  int off_prev = 0, e = -1, m_start = 0, m_end = 0, acc_t = 0;
#pragma unroll
  for (int i = 0; i < E_; i++) {
    int oe = eoff[i];
    int te = (oe - off_prev + 127) >> 7;
    if (e < 0 && mt < acc_t + te) {
      e = i; m_start = off_prev + (mt - acc_t) * 128; m_end = oe;
    }
    acc_t += te;
    off_prev = oe;
  }
  if (e < 0) return;

  const int tid = threadIdx.x;
  const int w = tid >> 6, lane = tid & 63;   // 16 waves
  const int wm = w >> 3, wn = w & 7;         // 2M x 8N waves, 64x32 out each
  const int quad = lane >> 4, l15 = lane & 15;
  const int srow = lane >> 3;                // row within 8-row staging chunk
  const int scol = ((lane & 7) ^ srow) * 8;  // SWIZZLED source bf16 col within BK=64

  f32x4 acc[4][2];
#pragma unroll
  for (int mi = 0; mi < 4; mi++)
#pragma unroll
    for (int ni = 0; ni < 2; ni++)
      acc[mi][ni] = (f32x4){0.f, 0.f, 0.f, 0.f};

  const unsigned short* Wb = Wbe + (long long)e * DOUT * KEXT;

  for (int kt = 0; kt < KT_N; kt++) {
    const int k0 = kt * 64;
#pragma unroll
    for (int j = 0; j < 3; j++) {
      int c = j * 16 + w;               // chunk 0..47: 0-15 A(128r), 16-47 B(256r)
      const unsigned short* src;
      unsigned short* dst;
      if (c < 16) {
        int rt = c * 8 + srow;          // A row 0..127
        int ga = m_start + rt; if (ga >= m_end) ga = m_end - 1;  // clamp partial
        src = Xe + (long long)ga * KEXT + k0 + scol;
        dst = &sAB[c * 512 + lane * 8];
      } else {
        int cb = c - 16;
        int rt = cb * 8 + srow;         // B row 0..255
        src = Wb + (long long)(n_start + rt) * KEXT + k0 + scol;
        dst = &sAB[8192 + cb * 512 + lane * 8];
      }
      gld16(src, dst);
    }
    __syncthreads();
#pragma unroll
    for (int ks = 0; ks < 2; ks++) {
      // swizzled read: colchunk kc = ks*4+quad lives at slot kc^(row&7)
      const int kx = (((ks << 2) | quad) ^ (l15 & 7)) << 3;
      bf16x8 af[4], bfr[2];
#pragma unroll
      for (int mi = 0; mi < 4; mi++)
        af[mi] = *(const bf16x8*)&sAB[(wm * 64 + mi * 16 + l15) * 64 + kx];
#pragma unroll
      for (int ni = 0; ni < 2; ni++)
        bfr[ni] = *(const bf16x8*)&sAB[8192 + (wn * 32 + ni * 16 + l15) * 64 + kx];
#pragma unroll
      for (int mi = 0; mi < 4; mi++)
#pragma unroll
        for (int ni = 0; ni < 2; ni++)
          acc[mi][ni] = __builtin_amdgcn_mfma_f32_16x16x32_bf16(
              af[mi], bfr[ni], acc[mi][ni], 0, 0, 0);
    }
    __syncthreads();
  }

  // ---- epilogue: gate + atomic scatter (gate/tok straight from global) ----
#pragma unroll
  for (int mi = 0; mi < 4; mi++) {
#pragma unroll
    for (int t4 = 0; t4 < 4; t4++) {
      const int row = wm * 64 + mi * 16 + quad * 4 + t4;
      if (m_start + row >= m_end) continue;    // partial tile guard
      const int rg = m_start + row;
      const float g = gate[rg];                // lanes of a quad share rg: broadcast
      float* orow = out + (long long)tok[rg] * DOUT + n_start + wn * 32 + l15;
#pragma unroll
      for (int ni = 0; ni < 2; ni++)
        atomicAdd(orow + ni * 16, acc[mi][ni][t4] * g);  // exactly k=2 adds/elem
    }
  }
}

extern "C" void kernel_launch(void* const* d_in, const int* in_sizes, int n_in,
                              void* d_out, int out_size, void* d_ws, size_t ws_size,
                              hipStream_t stream) {
  (void)in_sizes; (void)n_in; (void)out_size; (void)ws_size;
  const float* inputs = (const float*)d_in[0];
  const float* weight = (const float*)d_in[1];
  const float* lora_A = (const float*)d_in[2];
  const float* lora_B = (const float*)d_in[3];
  const float* gates  = (const float*)d_in[4];
  const int* sei  = (const int*)d_in[5];
  const int* ssi  = (const int*)d_in[6];
  const int* eoff = (const int*)d_in[7];
  const int* kptr = (const int*)d_in[8];
  (void)sei;
  float* out = (float*)d_out;

  // workspace layout (~104.4 MB)
  unsigned char* ws = (unsigned char*)d_ws;
  unsigned short* Wbe = (unsigned short*)ws;                 // 8*2048*2112*2 = 69,206,016 B
  unsigned short* Xe  = (unsigned short*)(ws + 69206016);    // 8192*2112*2   = 34,603,008 B
  float* gate = (float*)(ws + 104333312);                    // 8192*4
  int*   tok  = (int*)(ws + 104366080);                      // 8192*4

  hipMemsetAsync(d_out, 0, (size_t)N_TOK * DOUT * sizeof(float), stream);
  k_prep<<<XA_B + WCONV_B + GATHER_B, 256, 0, stream>>>(
      weight, lora_B, Wbe, lora_A, inputs, ssi, gates, kptr, Xe, gate, tok, eoff);
  k_gemm<<<576, 1024, 0, stream>>>(Xe, Wbe, gate, tok, eoff, out);
}

// Round 6
// 407.102 us; speedup vs baseline: 1.0696x; 1.0696x over previous
//
#include <hip/hip_runtime.h>
#include <hip/hip_bf16.h>

// Problem constants (fixed by setup_inputs)
#define E_    8
#define DIN   2048
#define DOUT  2048
#define N_TOK 4096
#define NK    8192
#define R_    16
#define KEXT  2112            // 2048 + 16 (LoRA rank tail) + 48 zero pad, %64==0
#define KT_N  (KEXT / 64)     // 33 K-tiles: 16 pairs + 1 tail

#define XA_B     519          // sum ceil(Me/16) <= 519 (xa blocks first: longest)
#define WCONV_B  4096
#define GATHER_B 8192

typedef __bf16 bf16x8 __attribute__((ext_vector_type(8)));
typedef float  f32x4  __attribute__((ext_vector_type(4)));
typedef unsigned short u16x8 __attribute__((ext_vector_type(8)));

static __device__ __forceinline__ void gld16(const void* g, void* l) {
  __builtin_amdgcn_global_load_lds(
      (const __attribute__((address_space(1))) unsigned int*)g,
      (__attribute__((address_space(3))) unsigned int*)l, 16, 0, 0);
}

static __device__ __forceinline__ unsigned short f2bfu(float f) {
  union { float f; unsigned int u; } v; v.f = f;
  unsigned int r = v.u + 0x7fffu + ((v.u >> 16) & 1u);  // round-to-nearest-even
  return (unsigned short)(r >> 16);
}

static __device__ __forceinline__ bf16x8 cvt8(float4 a, float4 b) {
  u16x8 u;
  u[0] = f2bfu(a.x); u[1] = f2bfu(a.y); u[2] = f2bfu(a.z); u[3] = f2bfu(a.w);
  u[4] = f2bfu(b.x); u[5] = f2bfu(b.y); u[6] = f2bfu(b.z); u[7] = f2bfu(b.w);
  return __builtin_bit_cast(bf16x8, u);
}

// ---- fully-parallel prep: xa | wconv | gather in ONE launch (FROZEN since r4:
// non-gemm time invariant ~258us across 4 structurally different preps ->
// harness reset/restore dominated, not prep code) ----
__global__ void __launch_bounds__(256)
k_prep(const float* __restrict__ w, const float* __restrict__ lb,
       unsigned short* __restrict__ wbe,
       const float* __restrict__ la,
       const float* __restrict__ x, const int* __restrict__ ssi,
       const float* __restrict__ gates, const int* __restrict__ kptr,
       unsigned short* __restrict__ Xe, float* __restrict__ gate,
       int* __restrict__ tok, const int* __restrict__ eoff) {
  const int b = blockIdx.x, tid = threadIdx.x;
  if (b < XA_B) {                                   // ---- XA tail ----
    __shared__ f32x4 red[4][64];
    int off_prev = 0, e = -1, m_start = 0, m_end = 0, acc_t = 0;
#pragma unroll
    for (int i = 0; i < E_; i++) {
      int oe = eoff[i];
      int te = (oe - off_prev + 15) >> 4;
      if (e < 0 && b < acc_t + te) {
        e = i; m_start = off_prev + (b - acc_t) * 16; m_end = oe;
      }
      acc_t += te; off_prev = oe;
    }
    if (e < 0) return;
    const int wv = tid >> 6, lane = tid & 63;
    const int l15 = lane & 15, quad = lane >> 4;
    int arow = m_start + l15; if (arow >= m_end) arow = m_end - 1;  // clamp
    const int kk = kptr[0];
    const int trow = ssi[arow] / kk;                // token row for this slot
    const float* xp = x  + (long long)trow * DIN + wv * 512 + quad * 8;
    const float* ap = la + ((long long)e * R_ + l15) * DIN + wv * 512 + quad * 8;
    f32x4 acc = (f32x4){0.f, 0.f, 0.f, 0.f};
#pragma unroll 4
    for (int k0 = 0; k0 < 512; k0 += 32) {
      float4 x0 = *(const float4*)(xp + k0);
      float4 x1 = *(const float4*)(xp + k0 + 4);
      float4 a0 = *(const float4*)(ap + k0);
      float4 a1 = *(const float4*)(ap + k0 + 4);
      acc = __builtin_amdgcn_mfma_f32_16x16x32_bf16(cvt8(x0, x1), cvt8(a0, a1),
                                                    acc, 0, 0, 0);
    }
    red[wv][lane] = acc;
    __syncthreads();
    if (wv == 0) {
      f32x4 s = red[0][lane] + red[1][lane] + red[2][lane] + red[3][lane];
#pragma unroll
      for (int t = 0; t < 4; t++) {
        int slot = m_start + quad * 4 + t;
        if (slot < m_end)
          Xe[(long long)slot * KEXT + 2048 + l15] = f2bfu(2.0f * s[t]);
      }
    }
  } else if (b < XA_B + WCONV_B) {                  // ---- wconv ----
    const int wv = tid >> 6, ln = tid & 63;
    const long long row = (((long long)(b - XA_B)) << 2) | wv;   // e*DOUT + n
    const float4* src  = (const float4*)(w + row * DIN);
    const float4* lsrc = (const float4*)(lb + row * R_);
    ushort4* dst = (ushort4*)(wbe + row * KEXT);
    for (int u = ln; u < KEXT / 4; u += 64) {
      float4 v;
      if (u < 512)       v = src[u];
      else if (u < 516)  v = lsrc[u - 512];
      else               v = make_float4(0.f, 0.f, 0.f, 0.f);
      ushort4 o;
      o.x = f2bfu(v.x); o.y = f2bfu(v.y); o.z = f2bfu(v.z); o.w = f2bfu(v.w);
      dst[u] = o;
    }
  } else {                                          // ---- gather ----
    const int s = b - XA_B - WCONV_B;
    int ssv = ssi[s];
    int kk = kptr[0];
    int t = ssv / kk, sl = ssv - t * kk;
    if (tid == 0) { gate[s] = gates[t * kk + sl]; tok[s] = t; }
    const float4* src = (const float4*)(x + (long long)t * DIN);
    ushort4* dst = (ushort4*)(Xe + (long long)s * KEXT);
    for (int i = tid; i < 512; i += 256) {
      float4 v = src[i];
      ushort4 o;
      o.x = f2bfu(v.x); o.y = f2bfu(v.y); o.z = f2bfu(v.z); o.w = f2bfu(v.w);
      dst[i] = o;
    }
    if (tid < 12) {   // zero cols 2064..2111 (cols 2048..2063 written by xa blocks)
      ushort4 z; z.x = z.y = z.z = z.w = 0;
      dst[516 + tid] = z;
    }
  }
}

// ---- grouped GEMM: r4 geometry (128x128, 512thr/8 waves, XOR swizzle, drain
// loop) with TWO K-tiles staged per barrier into a 64KB double-region. ----
// r4 vs r5 established: staging rate ~ in-flight bytes/CU; r4 = 4blk x 512thr x
// 4 gld16 = 128KB/CU bursts -> 9.2 TB/s. This variant: 2blk x 512thr x 8 gld16
// = same 128KB peak, but bursts are 2x deeper, barriers 2x rarer (17 vs 33),
// per-barrier MFMA 2x (32), and barrier domain stays 8 waves. Everything else
// byte-identical to r4 (best measured: 135us).
__global__ void __launch_bounds__(512)
k_gemm(const unsigned short* __restrict__ Xe, const unsigned short* __restrict__ Wbe,
       const float* __restrict__ gate, const int* __restrict__ tok,
       const int* __restrict__ eoff, float* __restrict__ out) {
  __shared__ alignas(16) unsigned short sAB[2 * 16384];  // 2 regions x (A|B), 64 KB

  const int id = blockIdx.x;                 // 1152 blocks
  const int xcd = id & 7, local = id >> 3;   // local 0..143
  const int mt = local % 72;
  const int nt = (xcd << 1) | (local / 72);  // 0..15
  const int n_start = nt << 7;

  // m-tile scan: mt covers sum(ceil(Me/128)) <= 71
  int off_prev = 0, e = -1, m_start = 0, m_end = 0, acc_t = 0;
#pragma unroll
  for (int i = 0; i < E_; i++) {
    int oe = eoff[i];
    int te = (oe - off_prev + 127) >> 7;
    if (e < 0 && mt < acc_t + te) {
      e = i; m_start = off_prev + (mt - acc_t) * 128; m_end = oe;
    }
    acc_t += te;
    off_prev = oe;
  }
  if (e < 0) return;

  const int tid = threadIdx.x;
  const int w = tid >> 6, lane = tid & 63;   // 8 waves
  const int wm = w >> 2, wn = w & 3;         // 2M x 4N waves, 64x32 out each
  const int quad = lane >> 4, l15 = lane & 15;
  const int srow = lane >> 3;                // row within 8-row staging chunk
  const int scol = ((lane & 7) ^ srow) * 8;  // SWIZZLED source bf16 col within BK=64

  f32x4 acc[4][2];
#pragma unroll
  for (int mi = 0; mi < 4; mi++)
#pragma unroll
    for (int ni = 0; ni < 2; ni++)
      acc[mi][ni] = (f32x4){0.f, 0.f, 0.f, 0.f};

  const unsigned short* Wb = Wbe + (long long)e * DOUT * KEXT;

  // 16 paired iterations: stage tiles {2t, 2t+1} (8 gld16/thread), one barrier,
  // compute 32 MFMA; then one tail iteration for tile 32 (BK=64, region 0).
  for (int kt2 = 0; kt2 < 16; kt2++) {
    const int k0 = kt2 * 128;
#pragma unroll
    for (int j = 0; j < 4; j++) {
      int c = w * 4 + j;                // chunk 0..31: 0-15 A, 16-31 B (1KB each)
      int rt = (c & 15) * 8 + srow;     // row-in-tile 0..127
      const unsigned short* src;
      if (c < 16) {
        int ga = m_start + rt; if (ga >= m_end) ga = m_end - 1;  // clamp partial
        src = Xe + (long long)ga * KEXT + k0 + scol;
      } else {
        src = Wb + (long long)(n_start + rt) * KEXT + k0 + scol;
      }
      gld16(src,      &sAB[c * 512 + lane * 8]);            // tile 2t   -> region 0
      gld16(src + 64, &sAB[16384 + c * 512 + lane * 8]);    // tile 2t+1 -> region 1
    }
    __syncthreads();
#pragma unroll
    for (int ks = 0; ks < 4; ks++) {
      const int base = (ks & 2) ? 16384 : 0;   // region select
      // swizzled read: colchunk kc = (ks&1)*4+quad lives at slot kc^(row&7)
      const int kx = (((((ks & 1) << 2) | quad)) ^ (l15 & 7)) << 3;
      bf16x8 af[4], bfr[2];
#pragma unroll
      for (int mi = 0; mi < 4; mi++)
        af[mi] = *(const bf16x8*)&sAB[base + (wm * 64 + mi * 16 + l15) * 64 + kx];
#pragma unroll
      for (int ni = 0; ni < 2; ni++)
        bfr[ni] = *(const bf16x8*)&sAB[base + 8192 + (wn * 32 + ni * 16 + l15) * 64 + kx];
#pragma unroll
      for (int mi = 0; mi < 4; mi++)
#pragma unroll
        for (int ni = 0; ni < 2; ni++)
          acc[mi][ni] = __builtin_amdgcn_mfma_f32_16x16x32_bf16(
              af[mi], bfr[ni], acc[mi][ni], 0, 0, 0);
    }
    __syncthreads();
  }
  {  // ---- tail tile kt=32 (cols 2048..2111: LoRA 16 + zero pad 48) ----
    const int k0 = 2048;
#pragma unroll
    for (int j = 0; j < 4; j++) {
      int c = w * 4 + j;
      int rt = (c & 15) * 8 + srow;
      const unsigned short* src;
      if (c < 16) {
        int ga = m_start + rt; if (ga >= m_end) ga = m_end - 1;
        src = Xe + (long long)ga * KEXT + k0 + scol;
      } else {
        src = Wb + (long long)(n_start + rt) * KEXT + k0 + scol;
      }
      gld16(src, &sAB[c * 512 + lane * 8]);
    }
    __syncthreads();
#pragma unroll
    for (int ks = 0; ks < 2; ks++) {
      const int kx = (((ks << 2) | quad) ^ (l15 & 7)) << 3;
      bf16x8 af[4], bfr[2];
#pragma unroll
      for (int mi = 0; mi < 4; mi++)
        af[mi] = *(const bf16x8*)&sAB[(wm * 64 + mi * 16 + l15) * 64 + kx];
#pragma unroll
      for (int ni = 0; ni < 2; ni++)
        bfr[ni] = *(const bf16x8*)&sAB[8192 + (wn * 32 + ni * 16 + l15) * 64 + kx];
#pragma unroll
      for (int mi = 0; mi < 4; mi++)
#pragma unroll
        for (int ni = 0; ni < 2; ni++)
          acc[mi][ni] = __builtin_amdgcn_mfma_f32_16x16x32_bf16(
              af[mi], bfr[ni], acc[mi][ni], 0, 0, 0);
    }
  }

  // ---- epilogue: gate + atomic scatter (gate/tok straight from global) ----
#pragma unroll
  for (int mi = 0; mi < 4; mi++) {
#pragma unroll
    for (int t4 = 0; t4 < 4; t4++) {
      const int row = wm * 64 + mi * 16 + quad * 4 + t4;
      if (m_start + row >= m_end) continue;    // partial tile guard
      const int rg = m_start + row;
      const float g = gate[rg];                // lanes of a quad share rg: broadcast
      float* orow = out + (long long)tok[rg] * DOUT + n_start + wn * 32 + l15;
#pragma unroll
      for (int ni = 0; ni < 2; ni++)
        atomicAdd(orow + ni * 16, acc[mi][ni][t4] * g);  // exactly k=2 adds/elem
    }
  }
}

extern "C" void kernel_launch(void* const* d_in, const int* in_sizes, int n_in,
                              void* d_out, int out_size, void* d_ws, size_t ws_size,
                              hipStream_t stream) {
  (void)in_sizes; (void)n_in; (void)out_size; (void)ws_size;
  const float* inputs = (const float*)d_in[0];
  const float* weight = (const float*)d_in[1];
  const float* lora_A = (const float*)d_in[2];
  const float* lora_B = (const float*)d_in[3];
  const float* gates  = (const float*)d_in[4];
  const int* sei  = (const int*)d_in[5];
  const int* ssi  = (const int*)d_in[6];
  const int* eoff = (const int*)d_in[7];
  const int* kptr = (const int*)d_in[8];
  (void)sei;
  float* out = (float*)d_out;

  // workspace layout (~104.4 MB)
  unsigned char* ws = (unsigned char*)d_ws;
  unsigned short* Wbe = (unsigned short*)ws;                 // 8*2048*2112*2 = 69,206,016 B
  unsigned short* Xe  = (unsigned short*)(ws + 69206016);    // 8192*2112*2   = 34,603,008 B
  float* gate = (float*)(ws + 104333312);                    // 8192*4
  int*   tok  = (int*)(ws + 104366080);                      // 8192*4

  hipMemsetAsync(d_out, 0, (size_t)N_TOK * DOUT * sizeof(float), stream);
  k_prep<<<XA_B + WCONV_B + GATHER_B, 256, 0, stream>>>(
      weight, lora_B, Wbe, lora_A, inputs, ssi, gates, kptr, Xe, gate, tok, eoff);
  k_gemm<<<1152, 512, 0, stream>>>(Xe, Wbe, gate, tok, eoff, out);
}